// Round 2
// baseline (433.178 us; speedup 1.0000x reference)
//
#include <hip/hip_runtime.h>
#include <hip/hip_bf16.h>

// GCN: N=50000, E=800000, hidden 64, 5 convs (relu on first 4).
// f32 tensors, int32 edge_index, f32 d_out[N].  ws_size in [19.8, 26.0) MB.
// r19: group-per-node restructure. r18 post-mortem: convs latency-bound (hbm 8.8%,
// VALU 42%, occ 45%); halving waves hurt; AND the transform reads all 16KB of W per
// node (50K x 16KB = 800MB/conv through a per-CU ~128B/cyc port = 12-15us floor in
// BOTH r17/r18). Fix both: each 8-lane group owns ONE node (8 nodes/wave parallel):
// lane i accumulates feats 8i..8i+7 over all its node's edges (no butterfly, 8x
// per-node latency amortization, same 8-rows-per-instr load shape). Wave then holds
// 8 act rows; transform amortizes each W-column read over 8 nodes (W LDS traffic /8).
// k_gconv_z / k_out get the same structure. CSR build + ticket fusion kept from r18.
// Workspace (~18.2 MB): gA bf16[N*64] | gB bf16[N*64] | bucket u16[E] | staging u32[E]
//   | row_start i32[N+1] | dinv f32[N] | zg f32[N] | bktcnt i32[256] | ticket i32
//   | bktbase i32[257] | bcur i32[256]

#define TPB 256
#define EPT 8                    // edges per thread in k_bktcnt / k_bin
#define CHUNK (TPB * EPT)        // 2048 edges per block
typedef __hip_bfloat16 bf16;
#define B2F __bfloat162float

__global__ void k_zero_b(int* __restrict__ bktcnt, int* __restrict__ ticket) {
    bktcnt[threadIdx.x] = 0;
    if (threadIdx.x == 0) *ticket = 0;
}

// Per-bucket (dst>>8) edge counts via LDS histogram; LAST block (ticket) also
// performs the 256-wide exclusive scan -> bktbase[257], bcur (fuses k_bktscan).
__global__ __launch_bounds__(TPB) void k_bktcnt(
    const int* __restrict__ dst, int* __restrict__ bktcnt, int* __restrict__ ticket,
    int* __restrict__ bktbase, int* __restrict__ bcur, int E, int n) {
    __shared__ int h[256];
    __shared__ int lastFlag;
    int tid = threadIdx.x;
    h[tid] = 0;
    __syncthreads();
    int e0 = blockIdx.x * CHUNK;
#pragma unroll
    for (int u = 0; u < EPT; ++u) {
        int e = e0 + u * TPB + tid;
        if (e < E) {
            int d = dst[e];
            if ((unsigned)d < (unsigned)n) atomicAdd(&h[d >> 8], 1);
        }
    }
    __syncthreads();
    if (h[tid]) atomicAdd(&bktcnt[tid], h[tid]);
    __threadfence();                               // counts visible before ticket
    __syncthreads();
    if (tid == 0) lastFlag = (atomicAdd(ticket, 1) == (int)gridDim.x - 1);
    __syncthreads();
    if (!lastFlag) return;                         // block-uniform exit
    // last block: coherent read of final counts, then scan (reuse h as buffer)
    int v = atomicAdd(&bktcnt[tid], 0);
    h[tid] = v;
    __syncthreads();
    for (int off = 1; off < 256; off <<= 1) {
        int u2 = (tid >= off) ? h[tid - off] : 0;
        __syncthreads();
        h[tid] += u2;
        __syncthreads();
    }
    int excl = h[tid] - v;
    bktbase[tid] = excl;
    bcur[tid] = excl;
    if (tid == 255) bktbase[256] = h[tid];
}

// Pass 1: bin edges by dst>>8 into staging (record = src | (dst&255)<<16).
__global__ __launch_bounds__(TPB) void k_bin(
    const int* __restrict__ src, const int* __restrict__ dst,
    int* __restrict__ bcur, unsigned* __restrict__ staging, int E, int n) {
    __shared__ int hcnt[256];
    __shared__ int hbase[256];
    int tid = threadIdx.x;
    int e0 = blockIdx.x * CHUNK;
    hcnt[tid] = 0;
    __syncthreads();

    int eb[EPT];
    unsigned rec[EPT];
#pragma unroll
    for (int u = 0; u < EPT; ++u) {
        int e = e0 + u * TPB + tid;
        eb[u] = -1;
        if (e < E) {
            int d = dst[e], s = src[e];
            if ((unsigned)d < (unsigned)n && (unsigned)s < (unsigned)n) {
                eb[u] = d >> 8;
                rec[u] = (unsigned)s | ((unsigned)(d & 255) << 16);
                atomicAdd(&hcnt[eb[u]], 1);
            }
        }
    }
    __syncthreads();
    int c = hcnt[tid];
    hbase[tid] = (c > 0) ? atomicAdd(&bcur[tid], c) : 0;
    hcnt[tid] = 0;
    __syncthreads();
#pragma unroll
    for (int u = 0; u < EPT; ++u) {
        if (eb[u] >= 0) {
            int r = atomicAdd(&hcnt[eb[u]], 1);
            int pos = hbase[eb[u]] + r;
            if ((unsigned)pos < (unsigned)E) staging[pos] = rec[u];  // replay-safe
        }
    }
}

// Pass 2: one block per bucket. Per-node histogram + prefix in LDS -> row_start,
// dinv, and record placement via LDS cursors (no global per-node atomics).
__global__ __launch_bounds__(TPB) void k_unbin2(
    const unsigned* __restrict__ staging, const int* __restrict__ bktbase,
    int* __restrict__ row_start, float* __restrict__ dinv,
    unsigned short* __restrict__ bucket, int E, int n) {
    __shared__ int cnt[256];
    __shared__ int scn[256];
    __shared__ int cur[256];
    int b = blockIdx.x, tid = threadIdx.x;
    int lo = bktbase[b], hi = bktbase[b + 1];
    lo = max(0, min(lo, E)); hi = max(lo, min(hi, E));

    cnt[tid] = 0;
    __syncthreads();
    for (int i = lo + tid; i < hi; i += TPB)
        atomicAdd(&cnt[(staging[i] >> 16) & 255], 1);
    __syncthreads();

    int v = cnt[tid];
    scn[tid] = v;
    __syncthreads();
    for (int off = 1; off < 256; off <<= 1) {
        int u = (tid >= off) ? scn[tid - off] : 0;
        __syncthreads();
        scn[tid] += u;
        __syncthreads();
    }
    int excl = scn[tid] - v;
    int base = min(lo + excl, E);
    cur[tid] = base;
    int d = (b << 8) + tid;
    if (d < n) {
        row_start[d] = base;
        dinv[d] = rsqrtf((float)v + 1.0f);     // +1 self-loop
        if (d == n - 1) row_start[n] = min(base + v, E);
    }
    __syncthreads();

    for (int i = lo + tid; i < hi; i += TPB) {
        unsigned r = staging[i];
        int t = (r >> 16) & 255;
        int pos = atomicAdd(&cur[t], 1);
        if ((unsigned)pos < (unsigned)E) bucket[pos] = (unsigned short)(r & 0xffffu);
    }
}

// g1[i][j] = (sum_{k<4} x[i][k] * W_in[k][j]) * dinv[i]   (premultiplied)
__global__ void k_mm_in(const float* __restrict__ x, const float* __restrict__ W,
                        const float* __restrict__ dinv, bf16* __restrict__ g, int n) {
    int t = blockIdx.x * blockDim.x + threadIdx.x;
    if (t >= n * 64) return;
    int i = t >> 6, j = t & 63;
    float acc = 0.f;
#pragma unroll
    for (int k = 0; k < 4; ++k) acc = fmaf(x[i * 4 + k], W[k * 64 + j], acc);
    g[t] = __float2bfloat16(acc * dinv[i]);
}

__device__ __forceinline__ void acc_oct(float* a, uint4 w) {
    a[0] += __uint_as_float(w.x << 16);
    a[1] += __uint_as_float(w.x & 0xffff0000u);
    a[2] += __uint_as_float(w.y << 16);
    a[3] += __uint_as_float(w.y & 0xffff0000u);
    a[4] += __uint_as_float(w.z << 16);
    a[5] += __uint_as_float(w.z & 0xffff0000u);
    a[6] += __uint_as_float(w.w << 16);
    a[7] += __uint_as_float(w.w & 0xffff0000u);
}

// Group-per-node gather: 8-lane group grp owns node d = base+grp entirely.
// Lane i (=lane&7) accumulates feats 8i..8i+7 into a[8] over self + all edges:
// per 8-edge chunk, one coalesced 16B bucket read, then 8x (width-8 shfl + oct
// row load). 8 groups -> 8 rows per load instruction, 8 nodes in flight per wave.
__device__ __forceinline__ void agg_grp(const bf16* __restrict__ g,
                                        const unsigned short* __restrict__ bucket,
                                        int k0, int k1, int dc, float* __restrict__ a,
                                        int i, unsigned nm1, unsigned Em1) {
#pragma unroll
    for (int m = 0; m < 8; ++m) a[m] = 0.f;
    {   // self term (clamped node row; store side is predicated)
        uint4 w = *(const uint4*)(g + (size_t)dc * 64 + 8 * i);
        acc_oct(a, w);
    }
    for (int t0 = k0; t0 < k1; t0 += 8) {
        int rec = bucket[min((unsigned)(t0 + i), Em1)];  // 16B per group, coalesced
        int m = k1 - t0;                                 // >=1, per-group uniform
#pragma unroll
        for (int e = 0; e < 8; ++e) {
            unsigned s = min((unsigned)__shfl(rec, e, 8), nm1);
            uint4 w = *(const uint4*)(g + (size_t)s * 64 + 8 * i);
            if (e < m) acc_oct(a, w);
        }
    }
}

// Fused layer: 8 nodes per wave (group-per-node), 32 nodes per block.
// W staged once per block in LDS (16KB). Transform: lane j computes feat j for
// all 8 of its wave's nodes -> each W column read ONCE per 8 nodes (8x less W
// traffic than per-node). Act rows live in wave-local LDS, read as broadcast
// float4 (wave-uniform addr). No barrier after the W-stage one (all wave-local).
__global__ __launch_bounds__(TPB) void k_gconv(
    const bf16* __restrict__ gIn, const float* __restrict__ dinv,
    const int* __restrict__ row_start, const unsigned short* __restrict__ bucket,
    const float* __restrict__ bias, const float* __restrict__ W,
    bf16* __restrict__ gOut, int n, int E) {
    __shared__ float sW[4096];           // 16 KB
    __shared__ float sAct[4][8][68];     // 8.7 KB; +4 pad spreads write banks
    int tid = threadIdx.x;
    const float4* W4 = (const float4*)W;
    float4* sW4 = (float4*)sW;
#pragma unroll
    for (int t = 0; t < 4; ++t) sW4[tid + t * 256] = W4[tid + t * 256];
    __syncthreads();

    int r = tid >> 6, j = tid & 63;
    int grp = j >> 3, i = j & 7;
    int base = (blockIdx.x * 4 + r) * 8;
    if (base >= n) return;               // wave-uniform, after the barrier
    unsigned nm1 = (unsigned)(n - 1), Em1 = (unsigned)(E - 1);
    int d = base + grp;
    int dc = min(d, n - 1);
    float dd = dinv[dc];
    int k0 = row_start[dc], k1 = row_start[dc + 1];
    k1 = min(k1, E); k0 = max(min(k0, k1), 0);
    if (d >= n) k1 = k0;                 // tail groups: no edges

    float a[8];
    agg_grp(gIn, bucket, k0, k1, dc, a, i, nm1, Em1);

    // act[d][8i+m] = relu(dd*a[m] + bias[8i+m]) -> wave-local LDS row
    const float4* b4 = (const float4*)bias;
    float4 bA = b4[2 * i], bB = b4[2 * i + 1];
    float4 r0, r1;
    r0.x = fmaxf(fmaf(dd, a[0], bA.x), 0.f);
    r0.y = fmaxf(fmaf(dd, a[1], bA.y), 0.f);
    r0.z = fmaxf(fmaf(dd, a[2], bA.z), 0.f);
    r0.w = fmaxf(fmaf(dd, a[3], bA.w), 0.f);
    r1.x = fmaxf(fmaf(dd, a[4], bB.x), 0.f);
    r1.y = fmaxf(fmaf(dd, a[5], bB.y), 0.f);
    r1.z = fmaxf(fmaf(dd, a[6], bB.z), 0.f);
    r1.w = fmaxf(fmaf(dd, a[7], bB.w), 0.f);
    float4* arow = (float4*)&sAct[r][grp][8 * i];
    arow[0] = r0; arow[1] = r1;
    // wave-local LDS RAW -> in-order lgkmcnt, no barrier (r15-r18 precedent)

    // transform: out[g][j] = sum_k act[g][k] * W[k][j]; W col read once per 8 nodes
    float acc[8] = {0.f, 0.f, 0.f, 0.f, 0.f, 0.f, 0.f, 0.f};
#pragma unroll
    for (int k4 = 0; k4 < 16; ++k4) {
        float w0 = sW[(4 * k4 + 0) * 64 + j];
        float w1 = sW[(4 * k4 + 1) * 64 + j];
        float w2 = sW[(4 * k4 + 2) * 64 + j];
        float w3 = sW[(4 * k4 + 3) * 64 + j];
#pragma unroll
        for (int g = 0; g < 8; ++g) {
            float4 av = *(const float4*)&sAct[r][g][4 * k4];  // broadcast
            acc[g] = fmaf(av.x, w0, acc[g]);
            acc[g] = fmaf(av.y, w1, acc[g]);
            acc[g] = fmaf(av.z, w2, acc[g]);
            acc[g] = fmaf(av.w, w3, acc[g]);
        }
    }
#pragma unroll
    for (int g = 0; g < 8; ++g) {
        float ddg = __shfl(dd, g * 8);   // node g's dinv (from its group's lane 0)
        if (base + g < n)
            gOut[(size_t)(base + g) * 64 + j] = __float2bfloat16(acc[g] * ddg);
    }
}

// Last hidden conv fused with 64->1 matmul: zg[d] = (relu(dd*sum+b) . Wout) * dd.
// Group-per-node; per-lane 8-feat dot, then 3-step width-8 shfl reduce. No LDS.
__global__ __launch_bounds__(TPB) void k_gconv_z(
    const bf16* __restrict__ gIn, const float* __restrict__ dinv,
    const int* __restrict__ row_start, const unsigned short* __restrict__ bucket,
    const float* __restrict__ bias, const float* __restrict__ Wout,
    float* __restrict__ zg, int n, int E) {
    int tid = threadIdx.x;
    int r = tid >> 6, j = tid & 63;
    int grp = j >> 3, i = j & 7;
    int base = (blockIdx.x * 4 + r) * 8;
    if (base >= n) return;               // wave-uniform (no barriers in kernel)
    unsigned nm1 = (unsigned)(n - 1), Em1 = (unsigned)(E - 1);
    int d = base + grp;
    int dc = min(d, n - 1);
    float dd = dinv[dc];
    int k0 = row_start[dc], k1 = row_start[dc + 1];
    k1 = min(k1, E); k0 = max(min(k0, k1), 0);
    if (d >= n) k1 = k0;

    float a[8];
    agg_grp(gIn, bucket, k0, k1, dc, a, i, nm1, Em1);

    const float4* b4 = (const float4*)bias;
    const float4* w4 = (const float4*)Wout;
    float4 bA = b4[2 * i], bB = b4[2 * i + 1];
    float4 wA = w4[2 * i], wB = w4[2 * i + 1];
    float p = fmaxf(fmaf(dd, a[0], bA.x), 0.f) * wA.x
            + fmaxf(fmaf(dd, a[1], bA.y), 0.f) * wA.y
            + fmaxf(fmaf(dd, a[2], bA.z), 0.f) * wA.z
            + fmaxf(fmaf(dd, a[3], bA.w), 0.f) * wA.w
            + fmaxf(fmaf(dd, a[4], bB.x), 0.f) * wB.x
            + fmaxf(fmaf(dd, a[5], bB.y), 0.f) * wB.y
            + fmaxf(fmaf(dd, a[6], bB.z), 0.f) * wB.z
            + fmaxf(fmaf(dd, a[7], bB.w), 0.f) * wB.w;
    p += __shfl_xor(p, 1, 8);
    p += __shfl_xor(p, 2, 8);
    p += __shfl_xor(p, 4, 8);
    if (i == 0 && d < n) zg[d] = p * dd;
}

// out[d] = dd*(zg[d] + sum zg[s]) + b_out.  Group-per-node, lane = edge slot.
__global__ __launch_bounds__(TPB) void k_out(
    const float* __restrict__ zg, const float* __restrict__ dinv,
    const int* __restrict__ row_start, const unsigned short* __restrict__ bucket,
    const float* __restrict__ b_out, float* __restrict__ out, int n, int E) {
    int tid = threadIdx.x;
    int r = tid >> 6, j = tid & 63;
    int grp = j >> 3, i = j & 7;
    int base = (blockIdx.x * 4 + r) * 8;
    if (base >= n) return;
    int d = base + grp;
    int dc = min(d, n - 1);
    int k0 = row_start[dc], k1 = row_start[dc + 1];
    k1 = min(k1, E); k0 = max(min(k0, k1), 0);
    if (d >= n) k1 = k0;
    unsigned nm1 = (unsigned)(n - 1);
    float v = 0.f;
    for (int k = k0 + i; k < k1; k += 8)
        v += zg[min((unsigned)bucket[k], nm1)];
    v += __shfl_xor(v, 1, 8);
    v += __shfl_xor(v, 2, 8);
    v += __shfl_xor(v, 4, 8);
    if (i == 0 && d < n) out[d] = fmaf(zg[d] + v, dinv[d], b_out[0]);
}

extern "C" void kernel_launch(void* const* d_in, const int* in_sizes, int n_in,
                              void* d_out, int out_size, void* d_ws, size_t ws_size,
                              hipStream_t stream) {
    const float* x     = (const float*)d_in[0];
    const int*   ei    = (const int*)d_in[1];
    const float* W_in  = (const float*)d_in[2];
    const float* b_in  = (const float*)d_in[3];
    const float* W_h   = (const float*)d_in[4];
    const float* b_h   = (const float*)d_in[5];
    const float* W_out = (const float*)d_in[6];
    const float* b_out = (const float*)d_in[7];
    float* out = (float*)d_out;

    int N = in_sizes[0] / 4;
    int E = in_sizes[1] / 2;
    const int* src = ei;
    const int* dst = ei + E;

    char* ws = (char*)d_ws;
    bf16* gA               = (bf16*)ws;           ws += (size_t)N * 64 * 2;
    bf16* gB               = (bf16*)ws;           ws += (size_t)N * 64 * 2;
    unsigned short* bucket = (unsigned short*)ws; ws += (size_t)E * 2;
    unsigned* staging      = (unsigned*)ws;       ws += (size_t)E * 4;
    int*  row_start        = (int*)ws;            ws += (size_t)(N + 1) * 4;
    float* dinv            = (float*)ws;          ws += (size_t)N * 4;
    float* zg              = (float*)ws;          ws += (size_t)N * 4;
    int*  bktcnt           = (int*)ws;            ws += 256 * 4;
    int*  ticket           = (int*)ws;            ws += 4;
    int*  bktbase          = (int*)ws;            ws += 257 * 4;
    int*  bcur             = (int*)ws;            // 256 ints

    int B    = (N + 255) >> 8;           // dst buckets (196 for N=50000; <=256)
    int gNF  = (N * 64 + TPB - 1) / TPB;
    int gN32 = (N + 31) / 32;            // 32 nodes/block (8 per wave, group-par)
    int gBin = (E + CHUNK - 1) / CHUNK;  // 391

    // ---- CSR build + norms (bucket-centric; scan fused into count) ----
    k_zero_b<<<1, 256, 0, stream>>>(bktcnt, ticket);
    k_bktcnt<<<gBin, TPB, 0, stream>>>(dst, bktcnt, ticket, bktbase, bcur, E, N);
    k_bin<<<gBin, TPB, 0, stream>>>(src, dst, bcur, staging, E, N);
    k_unbin2<<<B, TPB, 0, stream>>>(staging, bktbase, row_start, dinv, bucket, E, N);

    // ---- layers (feature buffers premultiplied by dinv) ----
    k_mm_in<<<gNF, TPB, 0, stream>>>(x, W_in, dinv, gA, N);
    k_gconv<<<gN32, TPB, 0, stream>>>(gA, dinv, row_start, bucket, b_in, W_h, gB, N, E);
    k_gconv<<<gN32, TPB, 0, stream>>>(gB, dinv, row_start, bucket, b_h, W_h + 4096, gA, N, E);
    k_gconv<<<gN32, TPB, 0, stream>>>(gA, dinv, row_start, bucket, b_h + 64, W_h + 8192, gB, N, E);
    k_gconv_z<<<gN32, TPB, 0, stream>>>(gB, dinv, row_start, bucket, b_h + 128, W_out, zg, N, E);
    k_out<<<gN32, TPB, 0, stream>>>(zg, dinv, row_start, bucket, b_out, out, N, E);
}

// Round 3
// 270.674 us; speedup vs baseline: 1.6004x; 1.6004x over previous
//
#include <hip/hip_runtime.h>
#include <hip/hip_bf16.h>

// GCN: N=50000, E=800000, hidden 64, 5 convs (relu on first 4).
// f32 tensors, int32 edge_index, f32 d_out[N].  ws_size in [19.8, 26.0) MB.
// r20: persistent-wave conv. r19 post-mortem: group-per-node blew VGPR to 256,
// occupancy 8.9% -> latency death. Constraints learned: (a) keep ~50K-wave-scale
// parallelism with lean <=128-VGPR waves (r17 shape), (b) amortize W without
// fattening the per-node loop. Fix: grid-stride persistent waves (1024 blocks,
// launch_bounds(256,4) hard-caps VGPR at 128): lane j holds W[:,j] in 64 VGPRs
// loaded ONCE per wave (~13 nodes amortization -> no per-node W port traffic).
// Gather = proven r17 OCT; combine via PADDED partial rows sVp[.][8][68] (pad 68
// makes b128 partial writes start-bank disjoint; unpadded 64 serialized 2x).
// Lane j ends with full agg[j]; act round-trips LDS once (1 write + 16 broadcast
// b128 reads) for the register-W transform. gconv_z same combine; k_out r17 form.
// Workspace (~18.2 MB): gA bf16[N*64] | gB bf16[N*64] | bucket u16[E] | staging u32[E]
//   | row_start i32[N+1] | dinv f32[N] | zg f32[N] | bktcnt i32[256] | ticket i32
//   | bktbase i32[257] | bcur i32[256]

#define TPB 256
#define EPT 8                    // edges per thread in k_bktcnt / k_bin
#define CHUNK (TPB * EPT)        // 2048 edges per block
typedef __hip_bfloat16 bf16;
#define B2F __bfloat162float

__global__ void k_zero_b(int* __restrict__ bktcnt, int* __restrict__ ticket) {
    bktcnt[threadIdx.x] = 0;
    if (threadIdx.x == 0) *ticket = 0;
}

// Per-bucket (dst>>8) edge counts via LDS histogram; LAST block (ticket) also
// performs the 256-wide exclusive scan -> bktbase[257], bcur (fuses k_bktscan).
__global__ __launch_bounds__(TPB) void k_bktcnt(
    const int* __restrict__ dst, int* __restrict__ bktcnt, int* __restrict__ ticket,
    int* __restrict__ bktbase, int* __restrict__ bcur, int E, int n) {
    __shared__ int h[256];
    __shared__ int lastFlag;
    int tid = threadIdx.x;
    h[tid] = 0;
    __syncthreads();
    int e0 = blockIdx.x * CHUNK;
#pragma unroll
    for (int u = 0; u < EPT; ++u) {
        int e = e0 + u * TPB + tid;
        if (e < E) {
            int d = dst[e];
            if ((unsigned)d < (unsigned)n) atomicAdd(&h[d >> 8], 1);
        }
    }
    __syncthreads();
    if (h[tid]) atomicAdd(&bktcnt[tid], h[tid]);
    __threadfence();                               // counts visible before ticket
    __syncthreads();
    if (tid == 0) lastFlag = (atomicAdd(ticket, 1) == (int)gridDim.x - 1);
    __syncthreads();
    if (!lastFlag) return;                         // block-uniform exit
    // last block: coherent read of final counts, then scan (reuse h as buffer)
    int v = atomicAdd(&bktcnt[tid], 0);
    h[tid] = v;
    __syncthreads();
    for (int off = 1; off < 256; off <<= 1) {
        int u2 = (tid >= off) ? h[tid - off] : 0;
        __syncthreads();
        h[tid] += u2;
        __syncthreads();
    }
    int excl = h[tid] - v;
    bktbase[tid] = excl;
    bcur[tid] = excl;
    if (tid == 255) bktbase[256] = h[tid];
}

// Pass 1: bin edges by dst>>8 into staging (record = src | (dst&255)<<16).
__global__ __launch_bounds__(TPB) void k_bin(
    const int* __restrict__ src, const int* __restrict__ dst,
    int* __restrict__ bcur, unsigned* __restrict__ staging, int E, int n) {
    __shared__ int hcnt[256];
    __shared__ int hbase[256];
    int tid = threadIdx.x;
    int e0 = blockIdx.x * CHUNK;
    hcnt[tid] = 0;
    __syncthreads();

    int eb[EPT];
    unsigned rec[EPT];
#pragma unroll
    for (int u = 0; u < EPT; ++u) {
        int e = e0 + u * TPB + tid;
        eb[u] = -1;
        if (e < E) {
            int d = dst[e], s = src[e];
            if ((unsigned)d < (unsigned)n && (unsigned)s < (unsigned)n) {
                eb[u] = d >> 8;
                rec[u] = (unsigned)s | ((unsigned)(d & 255) << 16);
                atomicAdd(&hcnt[eb[u]], 1);
            }
        }
    }
    __syncthreads();
    int c = hcnt[tid];
    hbase[tid] = (c > 0) ? atomicAdd(&bcur[tid], c) : 0;
    hcnt[tid] = 0;
    __syncthreads();
#pragma unroll
    for (int u = 0; u < EPT; ++u) {
        if (eb[u] >= 0) {
            int r = atomicAdd(&hcnt[eb[u]], 1);
            int pos = hbase[eb[u]] + r;
            if ((unsigned)pos < (unsigned)E) staging[pos] = rec[u];  // replay-safe
        }
    }
}

// Pass 2: one block per bucket. Per-node histogram + prefix in LDS -> row_start,
// dinv, and record placement via LDS cursors (no global per-node atomics).
__global__ __launch_bounds__(TPB) void k_unbin2(
    const unsigned* __restrict__ staging, const int* __restrict__ bktbase,
    int* __restrict__ row_start, float* __restrict__ dinv,
    unsigned short* __restrict__ bucket, int E, int n) {
    __shared__ int cnt[256];
    __shared__ int scn[256];
    __shared__ int cur[256];
    int b = blockIdx.x, tid = threadIdx.x;
    int lo = bktbase[b], hi = bktbase[b + 1];
    lo = max(0, min(lo, E)); hi = max(lo, min(hi, E));

    cnt[tid] = 0;
    __syncthreads();
    for (int i = lo + tid; i < hi; i += TPB)
        atomicAdd(&cnt[(staging[i] >> 16) & 255], 1);
    __syncthreads();

    int v = cnt[tid];
    scn[tid] = v;
    __syncthreads();
    for (int off = 1; off < 256; off <<= 1) {
        int u = (tid >= off) ? scn[tid - off] : 0;
        __syncthreads();
        scn[tid] += u;
        __syncthreads();
    }
    int excl = scn[tid] - v;
    int base = min(lo + excl, E);
    cur[tid] = base;
    int d = (b << 8) + tid;
    if (d < n) {
        row_start[d] = base;
        dinv[d] = rsqrtf((float)v + 1.0f);     // +1 self-loop
        if (d == n - 1) row_start[n] = min(base + v, E);
    }
    __syncthreads();

    for (int i = lo + tid; i < hi; i += TPB) {
        unsigned r = staging[i];
        int t = (r >> 16) & 255;
        int pos = atomicAdd(&cur[t], 1);
        if ((unsigned)pos < (unsigned)E) bucket[pos] = (unsigned short)(r & 0xffffu);
    }
}

// g1[i][j] = (sum_{k<4} x[i][k] * W_in[k][j]) * dinv[i]   (premultiplied)
__global__ void k_mm_in(const float* __restrict__ x, const float* __restrict__ W,
                        const float* __restrict__ dinv, bf16* __restrict__ g, int n) {
    int t = blockIdx.x * blockDim.x + threadIdx.x;
    if (t >= n * 64) return;
    int i = t >> 6, j = t & 63;
    float acc = 0.f;
#pragma unroll
    for (int k = 0; k < 4; ++k) acc = fmaf(x[i * 4 + k], W[k * 64 + j], acc);
    g[t] = __float2bfloat16(acc * dinv[i]);
}

__device__ __forceinline__ void acc_oct(float* a, uint4 w) {
    a[0] += __uint_as_float(w.x << 16);
    a[1] += __uint_as_float(w.x & 0xffff0000u);
    a[2] += __uint_as_float(w.y << 16);
    a[3] += __uint_as_float(w.y & 0xffff0000u);
    a[4] += __uint_as_float(w.z << 16);
    a[5] += __uint_as_float(w.z & 0xffff0000u);
    a[6] += __uint_as_float(w.w << 16);
    a[7] += __uint_as_float(w.w & 0xffff0000u);
}

// OCT gather (r17/r18 proven shape): 8 edges per load instruction. Lane group
// grp=lane>>3 takes edge k+grp; lane i=lane&7 loads uint4 = 8 packed bf16 feats
// (8 lanes x 16B = full 128B row). Partials in registers: a[m] = partial of feat
// 8i+m over this group's edges; caller combines across groups via LDS rows.
__device__ __forceinline__ void agg_oct(const bf16* __restrict__ g,
                                        const unsigned short* __restrict__ bucket,
                                        int k0, int k1, int d, float* __restrict__ a,
                                        int lane, unsigned nm1, unsigned Em1) {
    int grp = lane >> 3, i = lane & 7;
#pragma unroll
    for (int m = 0; m < 8; ++m) a[m] = 0.f;
    if (grp == 0) {  // self term
        uint4 w = *(const uint4*)(g + (size_t)d * 64 + 8 * i);
        acc_oct(a, w);
    }
    for (int base = k0; base < k1; base += 64) {
        int cnt = min(64, k1 - base);
        int rec = bucket[min((unsigned)(base + lane), Em1)];  // coalesced u16 load
        int k = 0;
        for (; k + 16 <= cnt; k += 16) {                      // 16 edges, 2 oct loads
            unsigned s0 = min((unsigned)__shfl(rec, k + grp), nm1);
            unsigned s1 = min((unsigned)__shfl(rec, k + 8 + grp), nm1);
            uint4 w0 = *(const uint4*)(g + (size_t)s0 * 64 + 8 * i);
            uint4 w1 = *(const uint4*)(g + (size_t)s1 * 64 + 8 * i);
            acc_oct(a, w0);
            acc_oct(a, w1);
        }
        for (; k < cnt; k += 8) {                             // tail, predicated
            int e = k + grp;
            unsigned s = min((unsigned)__shfl(rec, min(e, 63)), nm1);
            uint4 w = *(const uint4*)(g + (size_t)s * 64 + 8 * i);
            if (e < cnt) acc_oct(a, w);
        }
    }
}

// Persistent fused layer: grid-stride waves, 1 node per wave-iteration.
// Lane j holds W[:,j] in 64 VGPRs + bias[j], loaded once per wave (~13 nodes).
// Combine: padded partial rows sVp[wave][8][68] (b128 writes start-bank disjoint;
// 8x b32 reads conflict-free) -> lane j holds full agg[j]. Act: 1 b32 write +
// 16 broadcast b128 reads feed the register-W transform. No barriers at all.
__global__ __launch_bounds__(TPB, 4) void k_gconv(
    const bf16* __restrict__ gIn, const float* __restrict__ dinv,
    const int* __restrict__ row_start, const unsigned short* __restrict__ bucket,
    const float* __restrict__ bias, const float* __restrict__ W,
    bf16* __restrict__ gOut, int n, int E) {
    __shared__ float sVp[4][8][68];      // 8704 B, padded
    int tid = threadIdx.x;
    int r = tid >> 6, j = tid & 63;
    int grp = j >> 3, i = j & 7;
    unsigned nm1 = (unsigned)(n - 1), Em1 = (unsigned)(E - 1);

    // per-wave invariants: W column + bias (amortized over all nodes of this wave)
    float wreg[64];
#pragma unroll
    for (int k = 0; k < 64; ++k) wreg[k] = W[k * 64 + j];   // coalesced per k
    float bj = bias[j];

    int nw = gridDim.x * 4;
    for (int d = blockIdx.x * 4 + r; d < n; d += nw) {      // wave-uniform loop
        float dd = dinv[d];
        int k0 = row_start[d], k1 = row_start[d + 1];
        k1 = min(k1, E); k0 = max(min(k0, k1), 0);

        float a[8];
        agg_oct(gIn, bucket, k0, k1, d, a, j, nm1, Em1);

        // partials -> padded LDS rows (wave-local, in-order DS => no barrier)
        float4* prow = (float4*)&sVp[r][grp][8 * i];
        prow[0] = make_float4(a[0], a[1], a[2], a[3]);
        prow[1] = make_float4(a[4], a[5], a[6], a[7]);
        float full = 0.f;
#pragma unroll
        for (int g = 0; g < 8; ++g) full += sVp[r][g][j];   // (4g+j)%32: 2-way, free

        float act = fmaxf(fmaf(dd, full, bj), 0.f);
        sVp[r][0][j] = act;               // reads above already issued (in-order)

        float acc0 = 0.f, acc1 = 0.f, acc2 = 0.f, acc3 = 0.f;
#pragma unroll
        for (int k4 = 0; k4 < 16; ++k4) {
            float4 av = *(const float4*)&sVp[r][0][4 * k4];   // broadcast b128
            acc0 = fmaf(av.x, wreg[4 * k4 + 0], acc0);
            acc1 = fmaf(av.y, wreg[4 * k4 + 1], acc1);
            acc2 = fmaf(av.z, wreg[4 * k4 + 2], acc2);
            acc3 = fmaf(av.w, wreg[4 * k4 + 3], acc3);
        }
        float acc = (acc0 + acc1) + (acc2 + acc3);
        gOut[(size_t)d * 64 + j] = __float2bfloat16(acc * dd);
    }
}

// Last hidden conv fused with 64->1 matmul: zg[d] = (relu(dd*sum+b) . Wout) * dd.
// Padded-row combine -> lane j holds agg[j]; dot with Wout[j]; wave reduce.
__global__ __launch_bounds__(TPB) void k_gconv_z(
    const bf16* __restrict__ gIn, const float* __restrict__ dinv,
    const int* __restrict__ row_start, const unsigned short* __restrict__ bucket,
    const float* __restrict__ bias, const float* __restrict__ Wout,
    float* __restrict__ zg, int n, int E) {
    __shared__ float sVp[4][8][68];
    int tid = threadIdx.x;
    int r = tid >> 6, j = tid & 63;
    int grp = j >> 3, i = j & 7;
    int d = blockIdx.x * 4 + r;
    if (d >= n) return;                   // wave-uniform (no barriers in kernel)
    float dd = dinv[d];
    int k0 = row_start[d], k1 = row_start[d + 1];
    k1 = min(k1, E); k0 = max(min(k0, k1), 0);

    float a[8];
    agg_oct(gIn, bucket, k0, k1, d, a, j, (unsigned)(n - 1), (unsigned)(E - 1));

    float4* prow = (float4*)&sVp[r][grp][8 * i];
    prow[0] = make_float4(a[0], a[1], a[2], a[3]);
    prow[1] = make_float4(a[4], a[5], a[6], a[7]);
    float full = 0.f;
#pragma unroll
    for (int g = 0; g < 8; ++g) full += sVp[r][g][j];

    float p = fmaxf(fmaf(dd, full, bias[j]), 0.f) * Wout[j];
#pragma unroll
    for (int off = 32; off > 0; off >>= 1) p += __shfl_down(p, off);
    if (j == 0) zg[d] = p * dd;
}

// out[d] = dd*(zg[d] + sum zg[s]) + b_out.  One wave per node, lane = edge slot.
__global__ __launch_bounds__(TPB) void k_out(
    const float* __restrict__ zg, const float* __restrict__ dinv,
    const int* __restrict__ row_start, const unsigned short* __restrict__ bucket,
    const float* __restrict__ b_out, float* __restrict__ out, int n, int E) {
    int t = blockIdx.x * blockDim.x + threadIdx.x;
    int d = t >> 6, lane = t & 63;
    if (d >= n) return;
    int k0 = row_start[d], k1 = row_start[d + 1];
    k1 = min(k1, E); k0 = max(min(k0, k1), 0);
    unsigned nm1 = (unsigned)(n - 1);
    float v = 0.f;
    for (int k = k0 + lane; k < k1; k += 64) {
        unsigned s = min((unsigned)bucket[k], nm1);
        v += zg[s];
    }
#pragma unroll
    for (int off = 32; off > 0; off >>= 1) v += __shfl_down(v, off);
    if (lane == 0) out[d] = fmaf(zg[d] + v, dinv[d], b_out[0]);
}

extern "C" void kernel_launch(void* const* d_in, const int* in_sizes, int n_in,
                              void* d_out, int out_size, void* d_ws, size_t ws_size,
                              hipStream_t stream) {
    const float* x     = (const float*)d_in[0];
    const int*   ei    = (const int*)d_in[1];
    const float* W_in  = (const float*)d_in[2];
    const float* b_in  = (const float*)d_in[3];
    const float* W_h   = (const float*)d_in[4];
    const float* b_h   = (const float*)d_in[5];
    const float* W_out = (const float*)d_in[6];
    const float* b_out = (const float*)d_in[7];
    float* out = (float*)d_out;

    int N = in_sizes[0] / 4;
    int E = in_sizes[1] / 2;
    const int* src = ei;
    const int* dst = ei + E;

    char* ws = (char*)d_ws;
    bf16* gA               = (bf16*)ws;           ws += (size_t)N * 64 * 2;
    bf16* gB               = (bf16*)ws;           ws += (size_t)N * 64 * 2;
    unsigned short* bucket = (unsigned short*)ws; ws += (size_t)E * 2;
    unsigned* staging      = (unsigned*)ws;       ws += (size_t)E * 4;
    int*  row_start        = (int*)ws;            ws += (size_t)(N + 1) * 4;
    float* dinv            = (float*)ws;          ws += (size_t)N * 4;
    float* zg              = (float*)ws;          ws += (size_t)N * 4;
    int*  bktcnt           = (int*)ws;            ws += 256 * 4;
    int*  ticket           = (int*)ws;            ws += 4;
    int*  bktbase          = (int*)ws;            ws += 257 * 4;
    int*  bcur             = (int*)ws;            // 256 ints

    int B     = (N + 255) >> 8;          // dst buckets (196 for N=50000; <=256)
    int gNF   = (N * 64 + TPB - 1) / TPB;
    int gN4   = (N + 3) / 4;             // 4 nodes/block (1 wave per node)
    int gPers = 1024;                    // persistent conv grid (4 blocks/CU)
    int gBin  = (E + CHUNK - 1) / CHUNK; // 391

    // ---- CSR build + norms (bucket-centric; scan fused into count) ----
    k_zero_b<<<1, 256, 0, stream>>>(bktcnt, ticket);
    k_bktcnt<<<gBin, TPB, 0, stream>>>(dst, bktcnt, ticket, bktbase, bcur, E, N);
    k_bin<<<gBin, TPB, 0, stream>>>(src, dst, bcur, staging, E, N);
    k_unbin2<<<B, TPB, 0, stream>>>(staging, bktbase, row_start, dinv, bucket, E, N);

    // ---- layers (feature buffers premultiplied by dinv) ----
    k_mm_in<<<gNF, TPB, 0, stream>>>(x, W_in, dinv, gA, N);
    k_gconv<<<gPers, TPB, 0, stream>>>(gA, dinv, row_start, bucket, b_in, W_h, gB, N, E);
    k_gconv<<<gPers, TPB, 0, stream>>>(gB, dinv, row_start, bucket, b_h, W_h + 4096, gA, N, E);
    k_gconv<<<gPers, TPB, 0, stream>>>(gA, dinv, row_start, bucket, b_h + 64, W_h + 8192, gB, N, E);
    k_gconv_z<<<gN4, TPB, 0, stream>>>(gB, dinv, row_start, bucket, b_h + 128, W_out, zg, N, E);
    k_out<<<gN4, TPB, 0, stream>>>(zg, dinv, row_start, bucket, b_out, out, N, E);
}

// Round 4
// 259.326 us; speedup vs baseline: 1.6704x; 1.0438x over previous
//
#include <hip/hip_runtime.h>
#include <hip/hip_bf16.h>

// GCN: N=50000, E=800000, hidden 64, 5 convs (relu on first 4).
// f32 tensors, int32 edge_index, f32 d_out[N].  ws_size in [19.8, 26.0) MB.
// r21: aggregate-first layer 1. Aggregation is LINEAR: Agg(x@W_in) == (Agg x)@W_in,
// so conv#1 gathers raw 4-dim f32 rows (16B/edge, f32-exact) instead of 128B bf16
// rows of x@W_in — and k_mm_in disappears (unbin2 writes xt[d]=x[d]*dinv[d]).
// k_gconv1: lane-parallel float4 gather + 24-shfl butterfly + 4-fma W_in transform,
// then the r20 persistent tail (W_h0 column in 64 VGPRs, act broadcast from LDS).
// Middle convs / gconv_z / k_out / CSR build unchanged from r20 (single-variable).
// Workspace (~19.0 MB): gA bf16[N*64] | gB bf16[N*64] | xt f32x4[N] | bucket u16[E]
//   | staging u32[E] | row_start i32[N+1] | dinv f32[N] | zg f32[N] | bktcnt i32[256]
//   | ticket i32 | bktbase i32[257] | bcur i32[256]

#define TPB 256
#define EPT 8                    // edges per thread in k_bktcnt / k_bin
#define CHUNK (TPB * EPT)        // 2048 edges per block
typedef __hip_bfloat16 bf16;
#define B2F __bfloat162float

__global__ void k_zero_b(int* __restrict__ bktcnt, int* __restrict__ ticket) {
    bktcnt[threadIdx.x] = 0;
    if (threadIdx.x == 0) *ticket = 0;
}

// Per-bucket (dst>>8) edge counts via LDS histogram; LAST block (ticket) also
// performs the 256-wide exclusive scan -> bktbase[257], bcur (fuses k_bktscan).
__global__ __launch_bounds__(TPB) void k_bktcnt(
    const int* __restrict__ dst, int* __restrict__ bktcnt, int* __restrict__ ticket,
    int* __restrict__ bktbase, int* __restrict__ bcur, int E, int n) {
    __shared__ int h[256];
    __shared__ int lastFlag;
    int tid = threadIdx.x;
    h[tid] = 0;
    __syncthreads();
    int e0 = blockIdx.x * CHUNK;
#pragma unroll
    for (int u = 0; u < EPT; ++u) {
        int e = e0 + u * TPB + tid;
        if (e < E) {
            int d = dst[e];
            if ((unsigned)d < (unsigned)n) atomicAdd(&h[d >> 8], 1);
        }
    }
    __syncthreads();
    if (h[tid]) atomicAdd(&bktcnt[tid], h[tid]);
    __threadfence();                               // counts visible before ticket
    __syncthreads();
    if (tid == 0) lastFlag = (atomicAdd(ticket, 1) == (int)gridDim.x - 1);
    __syncthreads();
    if (!lastFlag) return;                         // block-uniform exit
    // last block: coherent read of final counts, then scan (reuse h as buffer)
    int v = atomicAdd(&bktcnt[tid], 0);
    h[tid] = v;
    __syncthreads();
    for (int off = 1; off < 256; off <<= 1) {
        int u2 = (tid >= off) ? h[tid - off] : 0;
        __syncthreads();
        h[tid] += u2;
        __syncthreads();
    }
    int excl = h[tid] - v;
    bktbase[tid] = excl;
    bcur[tid] = excl;
    if (tid == 255) bktbase[256] = h[tid];
}

// Pass 1: bin edges by dst>>8 into staging (record = src | (dst&255)<<16).
__global__ __launch_bounds__(TPB) void k_bin(
    const int* __restrict__ src, const int* __restrict__ dst,
    int* __restrict__ bcur, unsigned* __restrict__ staging, int E, int n) {
    __shared__ int hcnt[256];
    __shared__ int hbase[256];
    int tid = threadIdx.x;
    int e0 = blockIdx.x * CHUNK;
    hcnt[tid] = 0;
    __syncthreads();

    int eb[EPT];
    unsigned rec[EPT];
#pragma unroll
    for (int u = 0; u < EPT; ++u) {
        int e = e0 + u * TPB + tid;
        eb[u] = -1;
        if (e < E) {
            int d = dst[e], s = src[e];
            if ((unsigned)d < (unsigned)n && (unsigned)s < (unsigned)n) {
                eb[u] = d >> 8;
                rec[u] = (unsigned)s | ((unsigned)(d & 255) << 16);
                atomicAdd(&hcnt[eb[u]], 1);
            }
        }
    }
    __syncthreads();
    int c = hcnt[tid];
    hbase[tid] = (c > 0) ? atomicAdd(&bcur[tid], c) : 0;
    hcnt[tid] = 0;
    __syncthreads();
#pragma unroll
    for (int u = 0; u < EPT; ++u) {
        if (eb[u] >= 0) {
            int r = atomicAdd(&hcnt[eb[u]], 1);
            int pos = hbase[eb[u]] + r;
            if ((unsigned)pos < (unsigned)E) staging[pos] = rec[u];  // replay-safe
        }
    }
}

// Pass 2: one block per bucket. Per-node histogram + prefix in LDS -> row_start,
// dinv, xt (=x*dinv), and record placement via LDS cursors.
__global__ __launch_bounds__(TPB) void k_unbin2(
    const unsigned* __restrict__ staging, const int* __restrict__ bktbase,
    const float* __restrict__ x, float4* __restrict__ xt,
    int* __restrict__ row_start, float* __restrict__ dinv,
    unsigned short* __restrict__ bucket, int E, int n) {
    __shared__ int cnt[256];
    __shared__ int scn[256];
    __shared__ int cur[256];
    int b = blockIdx.x, tid = threadIdx.x;
    int lo = bktbase[b], hi = bktbase[b + 1];
    lo = max(0, min(lo, E)); hi = max(lo, min(hi, E));

    cnt[tid] = 0;
    __syncthreads();
    for (int i = lo + tid; i < hi; i += TPB)
        atomicAdd(&cnt[(staging[i] >> 16) & 255], 1);
    __syncthreads();

    int v = cnt[tid];
    scn[tid] = v;
    __syncthreads();
    for (int off = 1; off < 256; off <<= 1) {
        int u = (tid >= off) ? scn[tid - off] : 0;
        __syncthreads();
        scn[tid] += u;
        __syncthreads();
    }
    int excl = scn[tid] - v;
    int base = min(lo + excl, E);
    cur[tid] = base;
    int d = (b << 8) + tid;
    if (d < n) {
        row_start[d] = base;
        float di = rsqrtf((float)v + 1.0f);    // +1 self-loop
        dinv[d] = di;
        float4 xv = ((const float4*)x)[d];     // x is f32[N][4], 16B aligned
        xv.x *= di; xv.y *= di; xv.z *= di; xv.w *= di;
        xt[d] = xv;                            // premultiplied raw features
        if (d == n - 1) row_start[n] = min(base + v, E);
    }
    __syncthreads();

    for (int i = lo + tid; i < hi; i += TPB) {
        unsigned r = staging[i];
        int t = (r >> 16) & 255;
        int pos = atomicAdd(&cur[t], 1);
        if ((unsigned)pos < (unsigned)E) bucket[pos] = (unsigned short)(r & 0xffffu);
    }
}

__device__ __forceinline__ void acc_oct(float* a, uint4 w) {
    a[0] += __uint_as_float(w.x << 16);
    a[1] += __uint_as_float(w.x & 0xffff0000u);
    a[2] += __uint_as_float(w.y << 16);
    a[3] += __uint_as_float(w.y & 0xffff0000u);
    a[4] += __uint_as_float(w.z << 16);
    a[5] += __uint_as_float(w.z & 0xffff0000u);
    a[6] += __uint_as_float(w.w << 16);
    a[7] += __uint_as_float(w.w & 0xffff0000u);
}

// OCT gather (r17/r18 proven shape): 8 edges per load instruction. Lane group
// grp=lane>>3 takes edge k+grp; lane i=lane&7 loads uint4 = 8 packed bf16 feats
// (8 lanes x 16B = full 128B row). Partials in registers; caller combines across
// groups via padded LDS rows.
__device__ __forceinline__ void agg_oct(const bf16* __restrict__ g,
                                        const unsigned short* __restrict__ bucket,
                                        int k0, int k1, int d, float* __restrict__ a,
                                        int lane, unsigned nm1, unsigned Em1) {
    int grp = lane >> 3, i = lane & 7;
#pragma unroll
    for (int m = 0; m < 8; ++m) a[m] = 0.f;
    if (grp == 0) {  // self term
        uint4 w = *(const uint4*)(g + (size_t)d * 64 + 8 * i);
        acc_oct(a, w);
    }
    for (int base = k0; base < k1; base += 64) {
        int cnt = min(64, k1 - base);
        int rec = bucket[min((unsigned)(base + lane), Em1)];  // coalesced u16 load
        int k = 0;
        for (; k + 16 <= cnt; k += 16) {                      // 16 edges, 2 oct loads
            unsigned s0 = min((unsigned)__shfl(rec, k + grp), nm1);
            unsigned s1 = min((unsigned)__shfl(rec, k + 8 + grp), nm1);
            uint4 w0 = *(const uint4*)(g + (size_t)s0 * 64 + 8 * i);
            uint4 w1 = *(const uint4*)(g + (size_t)s1 * 64 + 8 * i);
            acc_oct(a, w0);
            acc_oct(a, w1);
        }
        for (; k < cnt; k += 8) {                             // tail, predicated
            int e = k + grp;
            unsigned s = min((unsigned)__shfl(rec, min(e, 63)), nm1);
            uint4 w = *(const uint4*)(g + (size_t)s * 64 + 8 * i);
            if (e < cnt) acc_oct(a, w);
        }
    }
}

// Layer 1, aggregate-first: agg4[d] = xt[d] + sum xt[s] (16B f32 rows, linearity of
// aggregation). Lane-parallel gather (lane = edge slot, float4 load), butterfly
// reduce, 4-fma W_in transform, relu; then the r20 persistent tail: W_h0 column in
// 64 VGPRs, act row broadcast from wave-local LDS. Persistent grid-stride waves.
__global__ __launch_bounds__(TPB, 4) void k_gconv1(
    const float4* __restrict__ xt, const float* __restrict__ dinv,
    const int* __restrict__ row_start, const unsigned short* __restrict__ bucket,
    const float* __restrict__ W_in, const float* __restrict__ b_in,
    const float* __restrict__ Wh0, bf16* __restrict__ gOut, int n, int E) {
    __shared__ float sAct[4][64];
    int tid = threadIdx.x;
    int r = tid >> 6, j = tid & 63;
    unsigned nm1 = (unsigned)(n - 1);

    // per-wave invariants
    float wreg[64];
#pragma unroll
    for (int k = 0; k < 64; ++k) wreg[k] = Wh0[k * 64 + j];
    float win0 = W_in[0 * 64 + j], win1 = W_in[1 * 64 + j];
    float win2 = W_in[2 * 64 + j], win3 = W_in[3 * 64 + j];
    float bj = b_in[j];

    int nw = gridDim.x * 4;
    for (int d = blockIdx.x * 4 + r; d < n; d += nw) {      // wave-uniform loop
        float dd = dinv[d];
        int k0 = row_start[d], k1 = row_start[d + 1];
        k1 = min(k1, E); k0 = max(min(k0, k1), 0);

        float4 v = make_float4(0.f, 0.f, 0.f, 0.f);
        if (j == 0) v = xt[d];                              // self term
        for (int k = k0 + j; k < k1; k += 64) {
            unsigned s = min((unsigned)bucket[k], nm1);
            float4 t = xt[s];
            v.x += t.x; v.y += t.y; v.z += t.z; v.w += t.w;
        }
#pragma unroll
        for (int off = 1; off < 64; off <<= 1) {            // butterfly: all lanes
            v.x += __shfl_xor(v.x, off);
            v.y += __shfl_xor(v.y, off);
            v.z += __shfl_xor(v.z, off);
            v.w += __shfl_xor(v.w, off);
        }
        float dot = fmaf(v.x, win0, fmaf(v.y, win1, fmaf(v.z, win2, v.w * win3)));
        float act = fmaxf(fmaf(dd, dot, bj), 0.f);
        sAct[r][j] = act;                 // wave-local RAW -> lgkmcnt, no barrier

        float acc0 = 0.f, acc1 = 0.f, acc2 = 0.f, acc3 = 0.f;
        const float4* ap = (const float4*)&sAct[r][0];
#pragma unroll
        for (int k4 = 0; k4 < 16; ++k4) {
            float4 av = ap[k4];           // wave-uniform address -> broadcast b128
            acc0 = fmaf(av.x, wreg[4 * k4 + 0], acc0);
            acc1 = fmaf(av.y, wreg[4 * k4 + 1], acc1);
            acc2 = fmaf(av.z, wreg[4 * k4 + 2], acc2);
            acc3 = fmaf(av.w, wreg[4 * k4 + 3], acc3);
        }
        float acc = (acc0 + acc1) + (acc2 + acc3);
        gOut[(size_t)d * 64 + j] = __float2bfloat16(acc * dd);
    }
}

// Persistent fused middle layer (r20): grid-stride waves, W column in 64 VGPRs.
// Combine via padded partial rows sVp[wave][8][68]; act broadcast from LDS.
__global__ __launch_bounds__(TPB, 4) void k_gconv(
    const bf16* __restrict__ gIn, const float* __restrict__ dinv,
    const int* __restrict__ row_start, const unsigned short* __restrict__ bucket,
    const float* __restrict__ bias, const float* __restrict__ W,
    bf16* __restrict__ gOut, int n, int E) {
    __shared__ float sVp[4][8][68];      // 8704 B, padded
    int tid = threadIdx.x;
    int r = tid >> 6, j = tid & 63;
    int grp = j >> 3, i = j & 7;
    unsigned nm1 = (unsigned)(n - 1), Em1 = (unsigned)(E - 1);

    float wreg[64];
#pragma unroll
    for (int k = 0; k < 64; ++k) wreg[k] = W[k * 64 + j];   // coalesced per k
    float bj = bias[j];

    int nw = gridDim.x * 4;
    for (int d = blockIdx.x * 4 + r; d < n; d += nw) {      // wave-uniform loop
        float dd = dinv[d];
        int k0 = row_start[d], k1 = row_start[d + 1];
        k1 = min(k1, E); k0 = max(min(k0, k1), 0);

        float a[8];
        agg_oct(gIn, bucket, k0, k1, d, a, j, nm1, Em1);

        float4* prow = (float4*)&sVp[r][grp][8 * i];
        prow[0] = make_float4(a[0], a[1], a[2], a[3]);
        prow[1] = make_float4(a[4], a[5], a[6], a[7]);
        float full = 0.f;
#pragma unroll
        for (int g = 0; g < 8; ++g) full += sVp[r][g][j];   // 2-way bank: free

        float act = fmaxf(fmaf(dd, full, bj), 0.f);
        sVp[r][0][j] = act;               // reads above already issued (in-order)

        float acc0 = 0.f, acc1 = 0.f, acc2 = 0.f, acc3 = 0.f;
#pragma unroll
        for (int k4 = 0; k4 < 16; ++k4) {
            float4 av = *(const float4*)&sVp[r][0][4 * k4];   // broadcast b128
            acc0 = fmaf(av.x, wreg[4 * k4 + 0], acc0);
            acc1 = fmaf(av.y, wreg[4 * k4 + 1], acc1);
            acc2 = fmaf(av.z, wreg[4 * k4 + 2], acc2);
            acc3 = fmaf(av.w, wreg[4 * k4 + 3], acc3);
        }
        float acc = (acc0 + acc1) + (acc2 + acc3);
        gOut[(size_t)d * 64 + j] = __float2bfloat16(acc * dd);
    }
}

// Last hidden conv fused with 64->1 matmul: zg[d] = (relu(dd*sum+b) . Wout) * dd.
__global__ __launch_bounds__(TPB) void k_gconv_z(
    const bf16* __restrict__ gIn, const float* __restrict__ dinv,
    const int* __restrict__ row_start, const unsigned short* __restrict__ bucket,
    const float* __restrict__ bias, const float* __restrict__ Wout,
    float* __restrict__ zg, int n, int E) {
    __shared__ float sVp[4][8][68];
    int tid = threadIdx.x;
    int r = tid >> 6, j = tid & 63;
    int grp = j >> 3, i = j & 7;
    int d = blockIdx.x * 4 + r;
    if (d >= n) return;                   // wave-uniform (no barriers in kernel)
    float dd = dinv[d];
    int k0 = row_start[d], k1 = row_start[d + 1];
    k1 = min(k1, E); k0 = max(min(k0, k1), 0);

    float a[8];
    agg_oct(gIn, bucket, k0, k1, d, a, j, (unsigned)(n - 1), (unsigned)(E - 1));

    float4* prow = (float4*)&sVp[r][grp][8 * i];
    prow[0] = make_float4(a[0], a[1], a[2], a[3]);
    prow[1] = make_float4(a[4], a[5], a[6], a[7]);
    float full = 0.f;
#pragma unroll
    for (int g = 0; g < 8; ++g) full += sVp[r][g][j];

    float p = fmaxf(fmaf(dd, full, bias[j]), 0.f) * Wout[j];
#pragma unroll
    for (int off = 32; off > 0; off >>= 1) p += __shfl_down(p, off);
    if (j == 0) zg[d] = p * dd;
}

// out[d] = dd*(zg[d] + sum zg[s]) + b_out.  One wave per node, lane = edge slot.
__global__ __launch_bounds__(TPB) void k_out(
    const float* __restrict__ zg, const float* __restrict__ dinv,
    const int* __restrict__ row_start, const unsigned short* __restrict__ bucket,
    const float* __restrict__ b_out, float* __restrict__ out, int n, int E) {
    int t = blockIdx.x * blockDim.x + threadIdx.x;
    int d = t >> 6, lane = t & 63;
    if (d >= n) return;
    int k0 = row_start[d], k1 = row_start[d + 1];
    k1 = min(k1, E); k0 = max(min(k0, k1), 0);
    unsigned nm1 = (unsigned)(n - 1);
    float v = 0.f;
    for (int k = k0 + lane; k < k1; k += 64) {
        unsigned s = min((unsigned)bucket[k], nm1);
        v += zg[s];
    }
#pragma unroll
    for (int off = 32; off > 0; off >>= 1) v += __shfl_down(v, off);
    if (lane == 0) out[d] = fmaf(zg[d] + v, dinv[d], b_out[0]);
}

extern "C" void kernel_launch(void* const* d_in, const int* in_sizes, int n_in,
                              void* d_out, int out_size, void* d_ws, size_t ws_size,
                              hipStream_t stream) {
    const float* x     = (const float*)d_in[0];
    const int*   ei    = (const int*)d_in[1];
    const float* W_in  = (const float*)d_in[2];
    const float* b_in  = (const float*)d_in[3];
    const float* W_h   = (const float*)d_in[4];
    const float* b_h   = (const float*)d_in[5];
    const float* W_out = (const float*)d_in[6];
    const float* b_out = (const float*)d_in[7];
    float* out = (float*)d_out;

    int N = in_sizes[0] / 4;
    int E = in_sizes[1] / 2;
    const int* src = ei;
    const int* dst = ei + E;

    char* ws = (char*)d_ws;
    bf16* gA               = (bf16*)ws;           ws += (size_t)N * 64 * 2;
    bf16* gB               = (bf16*)ws;           ws += (size_t)N * 64 * 2;
    float4* xt             = (float4*)ws;         ws += (size_t)N * 16;
    unsigned short* bucket = (unsigned short*)ws; ws += (size_t)E * 2;
    unsigned* staging      = (unsigned*)ws;       ws += (size_t)E * 4;
    int*  row_start        = (int*)ws;            ws += (size_t)(N + 1) * 4;
    float* dinv            = (float*)ws;          ws += (size_t)N * 4;
    float* zg              = (float*)ws;          ws += (size_t)N * 4;
    int*  bktcnt           = (int*)ws;            ws += 256 * 4;
    int*  ticket           = (int*)ws;            ws += 4;
    int*  bktbase          = (int*)ws;            ws += 257 * 4;
    int*  bcur             = (int*)ws;            // 256 ints

    int B     = (N + 255) >> 8;          // dst buckets (196 for N=50000; <=256)
    int gN4   = (N + 3) / 4;             // 4 nodes/block (1 wave per node)
    int gPers = 1024;                    // persistent conv grid (4 blocks/CU)
    int gBin  = (E + CHUNK - 1) / CHUNK; // 391

    // ---- CSR build + norms (bucket-centric; scan fused into count) ----
    k_zero_b<<<1, 256, 0, stream>>>(bktcnt, ticket);
    k_bktcnt<<<gBin, TPB, 0, stream>>>(dst, bktcnt, ticket, bktbase, bcur, E, N);
    k_bin<<<gBin, TPB, 0, stream>>>(src, dst, bcur, staging, E, N);
    k_unbin2<<<B, TPB, 0, stream>>>(staging, bktbase, x, xt, row_start, dinv, bucket, E, N);

    // ---- layers (feature buffers premultiplied by dinv) ----
    k_gconv1<<<gPers, TPB, 0, stream>>>(xt, dinv, row_start, bucket, W_in, b_in, W_h, gB, N, E);
    k_gconv<<<gPers, TPB, 0, stream>>>(gB, dinv, row_start, bucket, b_h, W_h + 4096, gA, N, E);
    k_gconv<<<gPers, TPB, 0, stream>>>(gA, dinv, row_start, bucket, b_h + 64, W_h + 8192, gB, N, E);
    k_gconv_z<<<gN4, TPB, 0, stream>>>(gB, dinv, row_start, bucket, b_h + 128, W_out, zg, N, E);
    k_out<<<gN4, TPB, 0, stream>>>(zg, dinv, row_start, bucket, b_out, out, N, E);
}